// Round 1
// baseline (867.268 us; speedup 1.0000x reference)
//
#include <hip/hip_runtime.h>

// ---------------------------------------------------------------------------
// ShiftedWindowAttention (Swin block, no mask): B=32, H=W=56, C=384, ws=7,
// shift=3, heads=12, hd=32.  Pipeline:
//   prep:      weights -> bf16 transposed [n][k]; bias -> C-frag order (+mask)
//   qkv_gemm:  x(fp32) @ qkv_w -> Q,K,V bf16 in [win][head][49][32] (roll+window
//              scatter fused, scale folded into Q)
//   attn:      1 wave per (win,head): MFMA QK^T -> exp(+bias) -> rowsum ->
//              P via LDS -> MFMA PV -> /rowsum -> un-roll scatter to AO bf16
//   proj_gemm: AO @ proj_w + proj_b -> out fp32
// ---------------------------------------------------------------------------

typedef __attribute__((ext_vector_type(8))) short short8;
typedef __attribute__((ext_vector_type(4))) float floatx4;

#define CDIM  384
#define QKVN  1152
#define MROWS 100352      // 32*3136
#define LROW  3136        // 56*56

static constexpr size_t QKV_ELEMS = 38535168ull;   // 2048*12*49*32
static constexpr size_t OFF_Q    = 0;
static constexpr size_t OFF_K    = OFF_Q  + QKV_ELEMS * 2 + 4096;
static constexpr size_t OFF_V    = OFF_K  + QKV_ELEMS * 2 + 4096;
static constexpr size_t OFF_AO   = OFF_V  + QKV_ELEMS * 2 + 4096;
static constexpr size_t OFF_WQ   = OFF_AO + (size_t)MROWS * CDIM * 2 + 4096;
static constexpr size_t OFF_WP   = OFF_WQ + (size_t)QKVN * CDIM * 2 + 256;
static constexpr size_t OFF_BIAS = OFF_WP + (size_t)CDIM * CDIM * 2 + 256;
// total ws need: OFF_BIAS + 12*64*64*4 = ~309.7 MB

// fp32 -> bf16 bits, round-to-nearest-even (no header dependence)
__device__ __forceinline__ unsigned short f2bf(float f) {
  unsigned int u = __float_as_uint(f);
  unsigned int lsb = (u >> 16) & 1u;
  u += 0x7fffu + lsb;
  return (unsigned short)(u >> 16);
}

// ---------------------------------------------------------------------------
// prep: weight transpose/convert + bias in C-fragment order
// bias_packed[h][lane][(fm*4+fn)*4 + r]; row=fm*16+(lane>>4)*4+r, col=fn*16+(lane&15)
// rows/cols >=49 masked to -1e30 (exp -> 0)
// ---------------------------------------------------------------------------
__global__ __launch_bounds__(256) void prep_kernel(
    const float* __restrict__ qkv_w, const float* __restrict__ proj_w,
    const float* __restrict__ rbt, char* __restrict__ ws) {
  unsigned short* Wq = (unsigned short*)(ws + OFF_WQ);
  unsigned short* Wp = (unsigned short*)(ws + OFF_WP);
  float* biasp = (float*)(ws + OFF_BIAS);
  const int tid = blockIdx.x * blockDim.x + threadIdx.x;
  const int stride = gridDim.x * blockDim.x;
  for (int idx = tid; idx < QKVN * CDIM; idx += stride) {
    int n = idx / CDIM, k = idx - n * CDIM;
    Wq[idx] = f2bf(qkv_w[(size_t)k * QKVN + n]);
  }
  for (int idx = tid; idx < CDIM * CDIM; idx += stride) {
    int n = idx / CDIM, k = idx - n * CDIM;
    Wp[idx] = f2bf(proj_w[(size_t)k * CDIM + n]);
  }
  for (int idx = tid; idx < 12 * 64 * 64; idx += stride) {
    int h = idx / 4096;
    int rem = idx - h * 4096;
    int lane = rem / 64;
    int e = rem - lane * 64;        // (fm*4+fn)*4 + r
    int fm = e >> 4, fn = (e >> 2) & 3, r = e & 3;
    int row = fm * 16 + (lane >> 4) * 4 + r;
    int col = fn * 16 + (lane & 15);
    float v = -1e30f;
    if (row < 49 && col < 49) {
      int i = row / 7, j = row - i * 7;
      int k2 = col / 7, l2 = col - k2 * 7;
      int rpi = (i - k2 + 6) * 13 + (j - l2 + 6);
      v = rbt[rpi * 12 + h];
    }
    biasp[idx] = v;
  }
}

// ---------------------------------------------------------------------------
// QKV GEMM: 100352x1152 = x(100352x384,fp32) @ Wq_t^T.  BM=128 BN=64 BK=32,
// 256 threads = 4 waves (2x2), per-wave 64x32 = 4x2 frags of 16x16x32 bf16.
// Epilogue: +bias, Q*=1/sqrt(32), scatter to [win][head][n][d] bf16.
// ---------------------------------------------------------------------------
__global__ __launch_bounds__(256) void qkv_gemm(
    const float* __restrict__ x, const float* __restrict__ qkv_b,
    char* __restrict__ ws) {
  __shared__ unsigned short As[128][40];
  __shared__ unsigned short Bs[64][40];
  const unsigned short* Wq = (const unsigned short*)(ws + OFF_WQ);
  unsigned short* Qb = (unsigned short*)(ws + OFF_Q);
  unsigned short* Kb = (unsigned short*)(ws + OFF_K);
  unsigned short* Vb = (unsigned short*)(ws + OFF_V);
  const int t = threadIdx.x;
  const int m0 = blockIdx.x * 128;
  const int n0 = blockIdx.y * 64;
  const int lane = t & 63, li = lane & 15, qd = lane >> 4;
  const int wv = t >> 6, wm = wv >> 1, wn = wv & 1;
  const int ar = t >> 1, ac = (t & 1) * 16;
  const int br = t >> 2, bc = (t & 3) * 8;
  floatx4 acc[4][2] = {};
  for (int k0 = 0; k0 < CDIM; k0 += 32) {
    // stage A: 128x32 fp32 -> bf16 (each thread 16 floats)
    const float* asrc = x + (size_t)(m0 + ar) * CDIM + k0 + ac;
    float4 f0 = ((const float4*)asrc)[0];
    float4 f1 = ((const float4*)asrc)[1];
    float4 f2 = ((const float4*)asrc)[2];
    float4 f3 = ((const float4*)asrc)[3];
    unsigned int p0 = (unsigned)f2bf(f0.x) | ((unsigned)f2bf(f0.y) << 16);
    unsigned int p1 = (unsigned)f2bf(f0.z) | ((unsigned)f2bf(f0.w) << 16);
    unsigned int p2 = (unsigned)f2bf(f1.x) | ((unsigned)f2bf(f1.y) << 16);
    unsigned int p3 = (unsigned)f2bf(f1.z) | ((unsigned)f2bf(f1.w) << 16);
    unsigned int p4 = (unsigned)f2bf(f2.x) | ((unsigned)f2bf(f2.y) << 16);
    unsigned int p5 = (unsigned)f2bf(f2.z) | ((unsigned)f2bf(f2.w) << 16);
    unsigned int p6 = (unsigned)f2bf(f3.x) | ((unsigned)f2bf(f3.y) << 16);
    unsigned int p7 = (unsigned)f2bf(f3.z) | ((unsigned)f2bf(f3.w) << 16);
    uint4 lo = {p0, p1, p2, p3}, hi = {p4, p5, p6, p7};
    *(uint4*)&As[ar][ac] = lo;
    *(uint4*)&As[ar][ac + 8] = hi;
    // stage B: 64x32 bf16 rows from pre-transposed Wq_t[n][k]
    const unsigned short* bsrc = Wq + (size_t)(n0 + br) * CDIM + k0 + bc;
    *(uint4*)&Bs[br][bc] = *(const uint4*)bsrc;
    __syncthreads();
    short8 a[4], b[2];
#pragma unroll
    for (int f = 0; f < 4; f++)
      a[f] = *(const short8*)&As[wm * 64 + f * 16 + li][qd * 8];
#pragma unroll
    for (int f = 0; f < 2; f++)
      b[f] = *(const short8*)&Bs[wn * 32 + f * 16 + li][qd * 8];
#pragma unroll
    for (int i = 0; i < 4; i++)
#pragma unroll
      for (int j = 0; j < 2; j++)
        acc[i][j] = __builtin_amdgcn_mfma_f32_16x16x32_bf16(a[i], b[j], acc[i][j], 0, 0, 0);
    __syncthreads();
  }
  // epilogue: scatter to window layout
#pragma unroll
  for (int i = 0; i < 4; i++) {
    int winr[4], nidxr[4];
#pragma unroll
    for (int r = 0; r < 4; r++) {
      int m = m0 + wm * 64 + i * 16 + qd * 4 + r;
      int b_ = m / LROW, l = m - b_ * LROW;
      int y = l / 56, xx = l - y * 56;
      int yr = y + 53; if (yr >= 56) yr -= 56;   // roll -3
      int xr = xx + 53; if (xr >= 56) xr -= 56;
      winr[r] = b_ * 64 + (yr / 7) * 8 + (xr / 7);
      nidxr[r] = (yr % 7) * 7 + (xr % 7);
    }
#pragma unroll
    for (int j = 0; j < 2; j++) {
      int c = n0 + wn * 32 + j * 16 + li;
      int which = c / CDIM;
      int cc = c - which * CDIM;
      int head = cc >> 5, d = cc & 31;
      unsigned short* dst = which == 0 ? Qb : (which == 1 ? Kb : Vb);
      float bval = qkv_b[c];
      float mul = (which == 0) ? 0.17677669529663689f : 1.0f;  // 1/sqrt(32) folded into Q
#pragma unroll
      for (int r = 0; r < 4; r++) {
        size_t off = ((size_t)(winr[r] * 12 + head) * 49 + nidxr[r]) * 32 + d;
        dst[off] = f2bf((acc[i][j][r] + bval) * mul);
      }
    }
  }
}

// ---------------------------------------------------------------------------
// Attention: 1 wave per (window, head).  S=Q*K^T via MFMA (Q,K frags straight
// from global: A- and B-frags of A*B^T both read row-major rows).  Softmax
// without max-sub (logits tiny); padding cols/rows killed by -1e30 bias.
// P -> LDS (bf16) -> A-frags; V B-frags via scalar L1 loads.  O /= rowsum,
// un-roll scatter to AO[b][y][x][c] bf16.
// ---------------------------------------------------------------------------
__global__ __launch_bounds__(64) void attn_kernel(char* __restrict__ ws) {
  __shared__ unsigned short Plds[64][72];   // pad 72: stride 144 B -> 2-way max
  const int win = blockIdx.x;
  const int h = blockIdx.y;
  const int lane = threadIdx.x;
  const int li = lane & 15, qd = lane >> 4;
  const size_t whoff = (size_t)(win * 12 + h) * 49 * 32;
  const unsigned short* Qb = (const unsigned short*)(ws + OFF_Q) + whoff;
  const unsigned short* Kb = (const unsigned short*)(ws + OFF_K) + whoff;
  const unsigned short* Vb = (const unsigned short*)(ws + OFF_V) + whoff;
  const float* biasp = (const float*)(ws + OFF_BIAS) + ((size_t)h * 64 + lane) * 64;

  short8 qa[4], kb[4];
#pragma unroll
  for (int f = 0; f < 4; f++) {
    qa[f] = *(const short8*)(Qb + (f * 16 + li) * 32 + qd * 8);
    kb[f] = *(const short8*)(Kb + (f * 16 + li) * 32 + qd * 8);
  }
  floatx4 s[4][4] = {};
#pragma unroll
  for (int i = 0; i < 4; i++)
#pragma unroll
    for (int j = 0; j < 4; j++)
      s[i][j] = __builtin_amdgcn_mfma_f32_16x16x32_bf16(qa[i], kb[j], s[i][j], 0, 0, 0);

  // V B-frags: B[k=m][n=d], k contiguous per lane -> strided scalar loads (L1-hot)
  short8 vb[2][2];
#pragma unroll
  for (int ss = 0; ss < 2; ss++)
#pragma unroll
    for (int nf = 0; nf < 2; nf++) {
      short8 tmp;
#pragma unroll
      for (int j = 0; j < 8; j++)
        tmp[j] = (short)Vb[(ss * 32 + qd * 8 + j) * 32 + nf * 16 + li];
      vb[ss][nf] = tmp;
    }

  float rsum[4][4];
#pragma unroll
  for (int fm = 0; fm < 4; fm++) {
#pragma unroll
    for (int fn = 0; fn < 4; fn++) {
      floatx4 bv = *(const floatx4*)(biasp + (fm * 4 + fn) * 4);
#pragma unroll
      for (int r = 0; r < 4; r++)
        s[fm][fn][r] = __expf(s[fm][fn][r] + bv[r]);
    }
#pragma unroll
    for (int r = 0; r < 4; r++) {
      float v = s[fm][0][r] + s[fm][1][r] + s[fm][2][r] + s[fm][3][r];
      v += __shfl_xor(v, 1);
      v += __shfl_xor(v, 2);
      v += __shfl_xor(v, 4);
      v += __shfl_xor(v, 8);
      rsum[fm][r] = v;           // full row sum (cols>=49 contribute 0)
    }
#pragma unroll
    for (int fn = 0; fn < 4; fn++)
#pragma unroll
      for (int r = 0; r < 4; r++)
        Plds[fm * 16 + qd * 4 + r][fn * 16 + li] = f2bf(s[fm][fn][r]);
  }
  __syncthreads();

  floatx4 o[4][2] = {};
#pragma unroll
  for (int fm = 0; fm < 4; fm++)
#pragma unroll
    for (int ss = 0; ss < 2; ss++) {
      short8 pa = *(const short8*)&Plds[fm * 16 + li][ss * 32 + qd * 8];
#pragma unroll
      for (int nf = 0; nf < 2; nf++)
        o[fm][nf] = __builtin_amdgcn_mfma_f32_16x16x32_bf16(pa, vb[ss][nf], o[fm][nf], 0, 0, 0);
    }

  unsigned short* AO = (unsigned short*)(ws + OFF_AO);
  const int b_ = win >> 6, wrem = win & 63, wy = wrem >> 3, wx = wrem & 7;
#pragma unroll
  for (int fm = 0; fm < 4; fm++)
#pragma unroll
    for (int r = 0; r < 4; r++) {
      int n = fm * 16 + qd * 4 + r;
      if (n >= 49) continue;
      float inv = 1.0f / rsum[fm][r];
      int i_ = n / 7, j_ = n - i_ * 7;
      int y = wy * 7 + i_ + 3;  if (y >= 56) y -= 56;   // un-roll +3
      int xx = wx * 7 + j_ + 3; if (xx >= 56) xx -= 56;
      size_t base = ((size_t)b_ * LROW + y * 56 + xx) * CDIM + h * 32;
#pragma unroll
      for (int nf = 0; nf < 2; nf++)
        AO[base + nf * 16 + li] = f2bf(o[fm][nf][r] * inv);
    }
}

// ---------------------------------------------------------------------------
// Proj GEMM: out(100352x384, fp32) = AO(bf16) @ Wp_t^T + proj_b
// ---------------------------------------------------------------------------
__global__ __launch_bounds__(256) void proj_gemm(
    const float* __restrict__ proj_b, char* __restrict__ ws,
    float* __restrict__ out) {
  __shared__ unsigned short As[128][40];
  __shared__ unsigned short Bs[64][40];
  const unsigned short* AO = (const unsigned short*)(ws + OFF_AO);
  const unsigned short* Wp = (const unsigned short*)(ws + OFF_WP);
  const int t = threadIdx.x;
  const int m0 = blockIdx.x * 128;
  const int n0 = blockIdx.y * 64;
  const int lane = t & 63, li = lane & 15, qd = lane >> 4;
  const int wv = t >> 6, wm = wv >> 1, wn = wv & 1;
  const int ar = t >> 1, ac = (t & 1) * 16;
  const int br = t >> 2, bc = (t & 3) * 8;
  floatx4 acc[4][2] = {};
  for (int k0 = 0; k0 < CDIM; k0 += 32) {
    const unsigned short* asrc = AO + (size_t)(m0 + ar) * CDIM + k0 + ac;
    uint4 a0 = ((const uint4*)asrc)[0];
    uint4 a1 = ((const uint4*)asrc)[1];
    *(uint4*)&As[ar][ac] = a0;
    *(uint4*)&As[ar][ac + 8] = a1;
    const unsigned short* bsrc = Wp + (size_t)(n0 + br) * CDIM + k0 + bc;
    *(uint4*)&Bs[br][bc] = *(const uint4*)bsrc;
    __syncthreads();
    short8 a[4], b[2];
#pragma unroll
    for (int f = 0; f < 4; f++)
      a[f] = *(const short8*)&As[wm * 64 + f * 16 + li][qd * 8];
#pragma unroll
    for (int f = 0; f < 2; f++)
      b[f] = *(const short8*)&Bs[wn * 32 + f * 16 + li][qd * 8];
#pragma unroll
    for (int i = 0; i < 4; i++)
#pragma unroll
      for (int j = 0; j < 2; j++)
        acc[i][j] = __builtin_amdgcn_mfma_f32_16x16x32_bf16(a[i], b[j], acc[i][j], 0, 0, 0);
    __syncthreads();
  }
#pragma unroll
  for (int i = 0; i < 4; i++)
#pragma unroll
    for (int j = 0; j < 2; j++) {
      int c = n0 + wn * 32 + j * 16 + li;
      float bv = proj_b[c];
#pragma unroll
      for (int r = 0; r < 4; r++) {
        int m = m0 + wm * 64 + i * 16 + qd * 4 + r;
        out[(size_t)m * CDIM + c] = acc[i][j][r] + bv;
      }
    }
}

extern "C" void kernel_launch(void* const* d_in, const int* in_sizes, int n_in,
                              void* d_out, int out_size, void* d_ws, size_t ws_size,
                              hipStream_t stream) {
  const float* x      = (const float*)d_in[0];
  const float* qkv_w  = (const float*)d_in[1];
  const float* qkv_b  = (const float*)d_in[2];
  const float* proj_w = (const float*)d_in[3];
  const float* proj_b = (const float*)d_in[4];
  const float* rbt    = (const float*)d_in[5];
  // d_in[6]=H, d_in[7]=W -- fixed 56, unused
  char* ws = (char*)d_ws;
  float* out = (float*)d_out;

  prep_kernel<<<512, 256, 0, stream>>>(qkv_w, proj_w, rbt, ws);
  qkv_gemm<<<dim3(784, 18), 256, 0, stream>>>(x, qkv_b, ws);
  attn_kernel<<<dim3(2048, 12), 64, 0, stream>>>(ws);
  proj_gemm<<<dim3(784, 6), 256, 0, stream>>>(proj_b, ws, out);
}

// Round 3
// 671.577 us; speedup vs baseline: 1.2914x; 1.2914x over previous
//
#include <hip/hip_runtime.h>

// ---------------------------------------------------------------------------
// ShiftedWindowAttention (Swin block, no mask): B=32, H=W=56, C=384, ws=7,
// shift=3, heads=12, hd=32.
//   prep:      weights -> bf16 [n][k]; bias -> C-frag order (+mask);
//              x -> bf16 (XB, aliases AO region)
//   qkv_gemm:  XB @ Wq^T -> Q,K,V bf16 [win][head][49][32], 128x128 tiles,
//              XCD-grouped N-fastest swizzle for A reuse in per-XCD L2
//   attn:      4 waves/block, 1 wave per (win,head); V via LDS; QK^T MFMA ->
//              exp(+bias) -> rowsum -> P via LDS -> PV MFMA -> scatter AO
//   proj_gemm: AO @ Wp^T + proj_b -> out fp32 (same swizzled 128x128 GEMM)
// R3 fix: V LDS staging loop was idx<196, must be idx<392 (49 rows x 8 uint2)
//         -> rows 25..48 of V were uninitialized LDS (NaN source).
// ---------------------------------------------------------------------------

typedef __attribute__((ext_vector_type(8))) short short8;
typedef __attribute__((ext_vector_type(4))) float floatx4;

#define CDIM  384
#define QKVN  1152
#define MROWS 100352      // 32*3136
#define LROW  3136        // 56*56

static constexpr size_t QKV_ELEMS = 38535168ull;   // 2048*12*49*32
static constexpr size_t OFF_Q    = 0;
static constexpr size_t OFF_K    = OFF_Q  + QKV_ELEMS * 2 + 4096;
static constexpr size_t OFF_V    = OFF_K  + QKV_ELEMS * 2 + 4096;
static constexpr size_t OFF_AO   = OFF_V  + QKV_ELEMS * 2 + 4096;  // also XB (x as bf16) before attn runs
static constexpr size_t OFF_WQ   = OFF_AO + (size_t)MROWS * CDIM * 2 + 4096;
static constexpr size_t OFF_WP   = OFF_WQ + (size_t)QKVN * CDIM * 2 + 256;
static constexpr size_t OFF_BIAS = OFF_WP + (size_t)CDIM * CDIM * 2 + 256;

__device__ __forceinline__ unsigned short f2bf(float f) {
  unsigned int u = __float_as_uint(f);
  unsigned int lsb = (u >> 16) & 1u;
  u += 0x7fffu + lsb;
  return (unsigned short)(u >> 16);
}

// ---------------------------------------------------------------------------
// prep: weight transpose/convert + bias in C-frag order + x -> bf16
// ---------------------------------------------------------------------------
__global__ __launch_bounds__(256) void prep_kernel(
    const float* __restrict__ x, const float* __restrict__ qkv_w,
    const float* __restrict__ proj_w, const float* __restrict__ rbt,
    char* __restrict__ ws) {
  unsigned short* Wq = (unsigned short*)(ws + OFF_WQ);
  unsigned short* Wp = (unsigned short*)(ws + OFF_WP);
  unsigned short* XB = (unsigned short*)(ws + OFF_AO);
  float* biasp = (float*)(ws + OFF_BIAS);
  const int tid = blockIdx.x * blockDim.x + threadIdx.x;
  const int stride = gridDim.x * blockDim.x;
  for (int idx = tid; idx < QKVN * CDIM; idx += stride) {
    int n = idx / CDIM, k = idx - n * CDIM;
    Wq[idx] = f2bf(qkv_w[(size_t)k * QKVN + n]);
  }
  for (int idx = tid; idx < CDIM * CDIM; idx += stride) {
    int n = idx / CDIM, k = idx - n * CDIM;
    Wp[idx] = f2bf(proj_w[(size_t)k * CDIM + n]);
  }
  for (int idx = tid; idx < 12 * 64 * 64; idx += stride) {
    int h = idx / 4096;
    int rem = idx - h * 4096;
    int lane = rem / 64;
    int e = rem - lane * 64;        // (fm*4+fn)*4 + r
    int fm = e >> 4, fn = (e >> 2) & 3, r = e & 3;
    int row = fm * 16 + (lane >> 4) * 4 + r;
    int col = fn * 16 + (lane & 15);
    float v = -1e30f;
    if (row < 49 && col < 49) {
      int i = row / 7, j = row - i * 7;
      int k2 = col / 7, l2 = col - k2 * 7;
      int rpi = (i - k2 + 6) * 13 + (j - l2 + 6);
      v = rbt[rpi * 12 + h];
    }
    biasp[idx] = v;
  }
  // x fp32 -> bf16, 8 elems/iter
  const size_t n8 = (size_t)MROWS * CDIM / 8;   // 4,816,896
  for (size_t idx = tid; idx < n8; idx += stride) {
    const float4* s = (const float4*)(x + idx * 8);
    float4 f0 = s[0], f1 = s[1];
    uint4 o;
    o.x = (unsigned)f2bf(f0.x) | ((unsigned)f2bf(f0.y) << 16);
    o.y = (unsigned)f2bf(f0.z) | ((unsigned)f2bf(f0.w) << 16);
    o.z = (unsigned)f2bf(f1.x) | ((unsigned)f2bf(f1.y) << 16);
    o.w = (unsigned)f2bf(f1.z) | ((unsigned)f2bf(f1.w) << 16);
    ((uint4*)XB)[idx] = o;
  }
}

// ---------------------------------------------------------------------------
// QKV GEMM: 100352x1152 = XB(bf16) @ Wq^T.  BM=128 BN=128 BK=32, 256 thr =
// 4 waves 2x2, per-wave 64x64 = 4x4 frags of 16x16x32 bf16.
// Linear grid 7056, swizzle: xcd=L%8, slot=L/8, m=(slot/9)*8+xcd, n=slot%9
// -> all 9 N-blocks of an M-row-block on one XCD (A fetched once from HBM).
// Epilogue: +bias, Q*=1/sqrt(32), scatter to [win][head][n][d] bf16.
// ---------------------------------------------------------------------------
__global__ __launch_bounds__(256) void qkv_gemm(
    const float* __restrict__ qkv_b, char* __restrict__ ws) {
  __shared__ unsigned short As[128][40];
  __shared__ unsigned short Bs[128][40];
  const unsigned short* XB = (const unsigned short*)(ws + OFF_AO);
  const unsigned short* Wq = (const unsigned short*)(ws + OFF_WQ);
  unsigned short* Qb = (unsigned short*)(ws + OFF_Q);
  unsigned short* Kb = (unsigned short*)(ws + OFF_K);
  unsigned short* Vb = (unsigned short*)(ws + OFF_V);
  const int L = blockIdx.x;
  const int xcd = L & 7, slot = L >> 3;
  const int g9 = slot / 9;
  const int m0 = (g9 * 8 + xcd) * 128;
  const int n0 = (slot - g9 * 9) * 128;
  const int t = threadIdx.x;
  const int lane = t & 63, li = lane & 15, qd = lane >> 4;
  const int wv = t >> 6, wm = wv >> 1, wn = wv & 1;
  const int sr = t >> 1, sc = (t & 1) * 16;
  floatx4 acc[4][4] = {};
  for (int k0 = 0; k0 < CDIM; k0 += 32) {
    const unsigned short* asrc = XB + (size_t)(m0 + sr) * CDIM + k0 + sc;
    uint4 a0 = ((const uint4*)asrc)[0];
    uint4 a1 = ((const uint4*)asrc)[1];
    const unsigned short* bsrc = Wq + (size_t)(n0 + sr) * CDIM + k0 + sc;
    uint4 b0 = ((const uint4*)bsrc)[0];
    uint4 b1 = ((const uint4*)bsrc)[1];
    *(uint4*)&As[sr][sc] = a0;
    *(uint4*)&As[sr][sc + 8] = a1;
    *(uint4*)&Bs[sr][sc] = b0;
    *(uint4*)&Bs[sr][sc + 8] = b1;
    __syncthreads();
    short8 a[4], b[4];
#pragma unroll
    for (int f = 0; f < 4; f++)
      a[f] = *(const short8*)&As[wm * 64 + f * 16 + li][qd * 8];
#pragma unroll
    for (int f = 0; f < 4; f++)
      b[f] = *(const short8*)&Bs[wn * 64 + f * 16 + li][qd * 8];
#pragma unroll
    for (int i = 0; i < 4; i++)
#pragma unroll
      for (int j = 0; j < 4; j++)
        acc[i][j] = __builtin_amdgcn_mfma_f32_16x16x32_bf16(a[i], b[j], acc[i][j], 0, 0, 0);
    __syncthreads();
  }
  // epilogue: each 128-wide N-tile lies entirely in one of Q/K/V (384 = 3*128)
  const int which = n0 / CDIM;
  unsigned short* dst = which == 0 ? Qb : (which == 1 ? Kb : Vb);
  const float mul = (which == 0) ? 0.17677669529663689f : 1.0f;
#pragma unroll
  for (int i = 0; i < 4; i++) {
    int winr[4], nidxr[4];
#pragma unroll
    for (int r = 0; r < 4; r++) {
      int m = m0 + wm * 64 + i * 16 + qd * 4 + r;
      int b_ = m / LROW, l = m - b_ * LROW;
      int y = l / 56, xx = l - y * 56;
      int yr = y + 53; if (yr >= 56) yr -= 56;   // roll -3
      int xr = xx + 53; if (xr >= 56) xr -= 56;
      winr[r] = b_ * 64 + (yr / 7) * 8 + (xr / 7);
      nidxr[r] = (yr % 7) * 7 + (xr % 7);
    }
#pragma unroll
    for (int j = 0; j < 4; j++) {
      int c = n0 + wn * 64 + j * 16 + li;
      int cc = c - which * CDIM;
      int head = cc >> 5, d = cc & 31;
      float bval = qkv_b[c];
#pragma unroll
      for (int r = 0; r < 4; r++) {
        size_t off = ((size_t)(winr[r] * 12 + head) * 49 + nidxr[r]) * 32 + d;
        dst[off] = f2bf((acc[i][j][r] + bval) * mul);
      }
    }
  }
}

// ---------------------------------------------------------------------------
// Attention: 256 thr = 4 waves, wave wv handles head blockIdx.y*4+wv of
// window blockIdx.x.  Per-wave LDS region SMEM[wv]: first holds V (stride-34
// layout, rows 49..63 zeroed), V frags -> regs, then overwritten by P
// (stride-72).  No __syncthreads (no cross-wave sharing).
// ---------------------------------------------------------------------------
__global__ __launch_bounds__(256) void attn_kernel(char* __restrict__ ws) {
  __shared__ unsigned short SMEM[4][64 * 72];
  const int win = blockIdx.x;
  const int t = threadIdx.x, wv = t >> 6, lane = t & 63;
  const int h = blockIdx.y * 4 + wv;
  const int li = lane & 15, qd = lane >> 4;
  unsigned short* Sm = &SMEM[wv][0];
  const size_t whoff = (size_t)(win * 12 + h) * 49 * 32;
  const unsigned short* Qb = (const unsigned short*)(ws + OFF_Q) + whoff;
  const unsigned short* Kb = (const unsigned short*)(ws + OFF_K) + whoff;
  const unsigned short* Vb = (const unsigned short*)(ws + OFF_V) + whoff;
  const float* biasp = (const float*)(ws + OFF_BIAS) + ((size_t)h * 64 + lane) * 64;

  // stage V: 49 rows x 32 cols bf16 = 392 uint2, LDS stride 34
  {
    const uint2* vsrc = (const uint2*)Vb;
    for (int idx = lane; idx < 392; idx += 64) {
      uint2 d = vsrc[idx];
      unsigned short* p = Sm + (idx >> 3) * 34 + (idx & 7) * 4;
      *(unsigned int*)p = d.x;
      *(unsigned int*)(p + 2) = d.y;
    }
    for (int idx = lane; idx < 120; idx += 64) {   // zero pad rows 49..63
      unsigned short* p = Sm + (49 + (idx >> 3)) * 34 + (idx & 7) * 4;
      *(unsigned int*)p = 0;
      *(unsigned int*)(p + 2) = 0;
    }
  }

  short8 qa[4], kb4[4];
#pragma unroll
  for (int f = 0; f < 4; f++) {
    qa[f] = *(const short8*)(Qb + (f * 16 + li) * 32 + qd * 8);
    kb4[f] = *(const short8*)(Kb + (f * 16 + li) * 32 + qd * 8);
  }
  floatx4 s[4][4] = {};
#pragma unroll
  for (int i = 0; i < 4; i++)
#pragma unroll
    for (int j = 0; j < 4; j++)
      s[i][j] = __builtin_amdgcn_mfma_f32_16x16x32_bf16(qa[i], kb4[j], s[i][j], 0, 0, 0);

  // V B-frags from LDS (before P overwrites the region)
  short8 vb[2][2];
#pragma unroll
  for (int ss = 0; ss < 2; ss++)
#pragma unroll
    for (int nf = 0; nf < 2; nf++) {
      short8 tmp;
#pragma unroll
      for (int j = 0; j < 8; j++)
        tmp[j] = (short)Sm[(ss * 32 + qd * 8 + j) * 34 + nf * 16 + li];
      vb[ss][nf] = tmp;
    }

  float rsum[4][4];
#pragma unroll
  for (int fm = 0; fm < 4; fm++) {
#pragma unroll
    for (int fn = 0; fn < 4; fn++) {
      floatx4 bv = *(const floatx4*)(biasp + (fm * 4 + fn) * 4);
#pragma unroll
      for (int r = 0; r < 4; r++)
        s[fm][fn][r] = __expf(s[fm][fn][r] + bv[r]);
    }
#pragma unroll
    for (int r = 0; r < 4; r++) {
      float v = s[fm][0][r] + s[fm][1][r] + s[fm][2][r] + s[fm][3][r];
      v += __shfl_xor(v, 1);
      v += __shfl_xor(v, 2);
      v += __shfl_xor(v, 4);
      v += __shfl_xor(v, 8);
      rsum[fm][r] = v;
    }
#pragma unroll
    for (int fn = 0; fn < 4; fn++)
#pragma unroll
      for (int r = 0; r < 4; r++)
        Sm[(fm * 16 + qd * 4 + r) * 72 + fn * 16 + li] = f2bf(s[fm][fn][r]);
  }

  floatx4 o[4][2] = {};
#pragma unroll
  for (int fm = 0; fm < 4; fm++)
#pragma unroll
    for (int ss = 0; ss < 2; ss++) {
      short8 pa = *(const short8*)&Sm[(fm * 16 + li) * 72 + ss * 32 + qd * 8];
#pragma unroll
      for (int nf = 0; nf < 2; nf++)
        o[fm][nf] = __builtin_amdgcn_mfma_f32_16x16x32_bf16(pa, vb[ss][nf], o[fm][nf], 0, 0, 0);
    }

  unsigned short* AO = (unsigned short*)(ws + OFF_AO);
  const int b_ = win >> 6, wrem = win & 63, wy = wrem >> 3, wx = wrem & 7;
#pragma unroll
  for (int fm = 0; fm < 4; fm++)
#pragma unroll
    for (int r = 0; r < 4; r++) {
      int n = fm * 16 + qd * 4 + r;
      if (n >= 49) continue;
      float inv = 1.0f / rsum[fm][r];
      int i_ = n / 7, j_ = n - i_ * 7;
      int y = wy * 7 + i_ + 3;  if (y >= 56) y -= 56;   // un-roll +3
      int xx = wx * 7 + j_ + 3; if (xx >= 56) xx -= 56;
      size_t base = ((size_t)b_ * LROW + y * 56 + xx) * CDIM + h * 32;
#pragma unroll
      for (int nf = 0; nf < 2; nf++)
        AO[base + nf * 16 + li] = f2bf(o[fm][nf][r] * inv);
    }
}

// ---------------------------------------------------------------------------
// Proj GEMM: out(100352x384 fp32) = AO(bf16) @ Wp^T + proj_b.  Same swizzled
// 128x128 structure; grid 2352: m=(slot/3)*8+xcd, n=slot%3.
// ---------------------------------------------------------------------------
__global__ __launch_bounds__(256) void proj_gemm(
    const float* __restrict__ proj_b, char* __restrict__ ws,
    float* __restrict__ out) {
  __shared__ unsigned short As[128][40];
  __shared__ unsigned short Bs[128][40];
  const unsigned short* AO = (const unsigned short*)(ws + OFF_AO);
  const unsigned short* Wp = (const unsigned short*)(ws + OFF_WP);
  const int L = blockIdx.x;
  const int xcd = L & 7, slot = L >> 3;
  const int g3 = slot / 3;
  const int m0 = (g3 * 8 + xcd) * 128;
  const int n0 = (slot - g3 * 3) * 128;
  const int t = threadIdx.x;
  const int lane = t & 63, li = lane & 15, qd = lane >> 4;
  const int wv = t >> 6, wm = wv >> 1, wn = wv & 1;
  const int sr = t >> 1, sc = (t & 1) * 16;
  floatx4 acc[4][4] = {};
  for (int k0 = 0; k0 < CDIM; k0 += 32) {
    const unsigned short* asrc = AO + (size_t)(m0 + sr) * CDIM + k0 + sc;
    uint4 a0 = ((const uint4*)asrc)[0];
    uint4 a1 = ((const uint4*)asrc)[1];
    const unsigned short* bsrc = Wp + (size_t)(n0 + sr) * CDIM + k0 + sc;
    uint4 b0 = ((const uint4*)bsrc)[0];
    uint4 b1 = ((const uint4*)bsrc)[1];
    *(uint4*)&As[sr][sc] = a0;
    *(uint4*)&As[sr][sc + 8] = a1;
    *(uint4*)&Bs[sr][sc] = b0;
    *(uint4*)&Bs[sr][sc + 8] = b1;
    __syncthreads();
    short8 a[4], b[4];
#pragma unroll
    for (int f = 0; f < 4; f++)
      a[f] = *(const short8*)&As[wm * 64 + f * 16 + li][qd * 8];
#pragma unroll
    for (int f = 0; f < 4; f++)
      b[f] = *(const short8*)&Bs[wn * 64 + f * 16 + li][qd * 8];
#pragma unroll
    for (int i = 0; i < 4; i++)
#pragma unroll
      for (int j = 0; j < 4; j++)
        acc[i][j] = __builtin_amdgcn_mfma_f32_16x16x32_bf16(a[i], b[j], acc[i][j], 0, 0, 0);
    __syncthreads();
  }
#pragma unroll
  for (int i = 0; i < 4; i++)
#pragma unroll
    for (int j = 0; j < 4; j++) {
      int c = n0 + wn * 64 + j * 16 + li;
      float bv = proj_b[c];
#pragma unroll
      for (int r = 0; r < 4; r++) {
        int m = m0 + wm * 64 + i * 16 + qd * 4 + r;
        out[(size_t)m * CDIM + c] = acc[i][j][r] + bv;
      }
    }
}

extern "C" void kernel_launch(void* const* d_in, const int* in_sizes, int n_in,
                              void* d_out, int out_size, void* d_ws, size_t ws_size,
                              hipStream_t stream) {
  const float* x      = (const float*)d_in[0];
  const float* qkv_w  = (const float*)d_in[1];
  const float* qkv_b  = (const float*)d_in[2];
  const float* proj_w = (const float*)d_in[3];
  const float* proj_b = (const float*)d_in[4];
  const float* rbt    = (const float*)d_in[5];
  char* ws = (char*)d_ws;
  float* out = (float*)d_out;

  prep_kernel<<<2048, 256, 0, stream>>>(x, qkv_w, proj_w, rbt, ws);
  qkv_gemm<<<7056, 256, 0, stream>>>(qkv_b, ws);
  attn_kernel<<<dim3(2048, 3), 256, 0, stream>>>(ws);
  proj_gemm<<<2352, 256, 0, stream>>>(proj_b, ws, out);
}